// Round 5
// baseline (199.420 us; speedup 1.0000x reference)
//
#include <hip/hip_runtime.h>

// Output: (B=512, H=128, W=128, C=5) fp32, flat. Thread owns one float4 of the
// FLAT array: F = 4*q + j, pixel p = F/5, channel ch = F%5. Direct coalesced
// stores (wave = contiguous 1024B), no LDS staging, no mid-loop barriers.
// ch0 = stamp[p]; ch1 = scatter (atomics at end); ch2 = xs[h>>2];
// ch3 = |xs[h>>2]-xs[w>>2]|*inv; ch4 = bar (col 17+3i is bar i, h < bh[i]).

__global__ __launch_bounds__(256) void di_main(const float* __restrict__ inputs,
                                               const float* __restrict__ stamp,
                                               const int* __restrict__ coords,
                                               float* __restrict__ out) {
    const int blk = blockIdx.x;     // 2048 blocks: 512 b x 4 quarters (32 rows each)
    const int b = blk >> 2;
    const int qt = blk & 3;
    const int tid = threadIdx.x;

    __shared__ float xs[32];
    __shared__ int bh[32];
    __shared__ float sinv;

    // ---- preamble: wave 0 computes bar heights and 1/(max-min) ----
    if (tid < 64) {
        float v = inputs[b * 32 + (tid & 31)];
        if (tid < 32) {
            xs[tid] = v;
            int t = (int)rintf(v * 128.0f);   // round-half-to-even, matches np.round
            bh[tid] = t < 0 ? 0 : (t > 128 ? 128 : t);
        }
        float mn = v, mx = v;
#pragma unroll
        for (int off = 1; off < 32; off <<= 1) {
            mn = fminf(mn, __shfl_xor(mn, off));
            mx = fmaxf(mx, __shfl_xor(mx, off));
        }
        if (tid == 0) sinv = 1.0f / (mx - mn);
    }
    __syncthreads();
    const float inv = sinv;

    // quarter qt: float4 indices [qt*5120, qt*5120+5120) within image b
    float4* outq = reinterpret_cast<float4*>(out) + (size_t)b * 20480 + (size_t)qt * 5120;

#pragma unroll 2
    for (int i = 0; i < 20; ++i) {
        const int q = i * 256 + tid;                 // f4 index within quarter
        const unsigned F = (unsigned)(qt * 5120 + q) * 4u;  // float index within image
        unsigned p = F / 5u;                          // pixel
        int ch = (int)(F - p * 5u);                   // channel

        float vjs[4];
#pragma unroll
        for (int j = 0; j < 4; ++j) {
            const int h = (int)(p >> 7);
            const int w = (int)(p & 127u);
            const float rowv = xs[h >> 2];
            const float ndv = fabsf(rowv - xs[w >> 2]) * inv;
            const int t = w - 17;
            const int bar = t / 3;
            float barv = 0.0f;
            if (t >= 0 && t - bar * 3 == 0 && bar < 32)
                barv = (h < bh[bar]) ? 1.0f : 0.0f;
            const float sval = stamp[p];              // L1/L2-hot, 64 KB total

            float val;
            if (ch == 0)      val = sval;
            else if (ch == 1) val = 0.0f;             // scatter adds later
            else if (ch == 2) val = rowv;
            else if (ch == 3) val = ndv;
            else              val = barv;
            vjs[j] = val;

            ++ch;
            if (ch == 5) { ch = 0; ++p; }             // advance to next float
        }
        float4 r;
        r.x = vjs[0]; r.y = vjs[1]; r.z = vjs[2]; r.w = vjs[3];
        outq[q] = r;                                  // wave: contiguous 1024B
    }

    // ---- fused scatter: barrier drains this block's stores, then atomics ----
    __syncthreads();
    if (tid < 32) {
        const int r = coords[2 * tid], c = coords[2 * tid + 1];
        if ((r >> 5) == qt)                           // quarter owns rows [qt*32, qt*32+32)
            atomicAdd(out + ((size_t)b * 16384 + (size_t)(r * 128 + c)) * 5 + 1, xs[tid]);
    }
}

extern "C" void kernel_launch(void* const* d_in, const int* in_sizes, int n_in,
                              void* d_out, int out_size, void* d_ws, size_t ws_size,
                              hipStream_t stream) {
    const float* inputs = (const float*)d_in[0];   // [512,32]
    const float* stamp  = (const float*)d_in[1];   // [128,128,1]
    const int*   coords = (const int*)d_in[2];     // [32,2]
    float* out = (float*)d_out;                    // [512,128,128,5]

    di_main<<<2048, 256, 0, stream>>>(inputs, stamp, coords, out);
}

// Round 6
// 166.240 us; speedup vs baseline: 1.1996x; 1.1996x over previous
//
#include <hip/hip_runtime.h>

// Output: (B=512, H=128, W=128, C=5) fp32.
// ch0 = stamp[h,w]; ch1 = scatter-add (post-store atomics); ch2 = x[b,h>>2];
// ch3 = |x[b,h>>2]-x[b,w>>2]| / (max-min); ch4 = bar (col 17+3i is bar i, h<bh[i]).
// Block = (b, part): 2048 pixels = rows [part*16, part*16+16) of image b.
// Two 1024-px chunks, double-buffered LDS staging -> coalesced 1024B wave stores,
// chunk-1 compute/LDS-write overlapped with chunk-0 stores.

__global__ __launch_bounds__(256) void di_main(const float* __restrict__ inputs,
                                               const float* __restrict__ stamp,
                                               const int* __restrict__ coords,
                                               float* __restrict__ out) {
    const int blk = blockIdx.x;     // 4096 blocks: 512 b x 8 parts
    const int b = blk >> 3;
    const int part = blk & 7;
    const int tid = threadIdx.x;
    const int lane = tid & 63;

    __shared__ float buf[2][256 * 20];   // 2 x 20 KB staging

    // ---- barrier-free preamble: per-wave redundant, all via shuffles ----
    const float v = inputs[b * 32 + (lane & 31)];   // lanes 32..63 duplicate
    int bt = (int)rintf(v * 128.0f);                // round-half-even = np.round
    bt = bt < 0 ? 0 : (bt > 128 ? 128 : bt);        // per-lane bar height
    float mn = v, mx = v;
#pragma unroll
    for (int off = 1; off < 32; off <<= 1) {        // within-half butterfly
        mn = fminf(mn, __shfl_xor(mn, off));
        mx = fmaxf(mx, __shfl_xor(mx, off));
    }
    const float inv = 1.0f / (mx - mn);             // dm min = 0 (diagonal)

    auto compute = [&](int c, float* vals) {
        const int lp = part * 2048 + c * 1024 + tid * 4;  // pixel in image
        const int h = lp >> 7;
        const int w0 = lp & 127;                          // multiple of 4
        const float rowv = __shfl(v, h >> 2);
        const float ndv = fabsf(rowv - __shfl(v, w0 >> 2)) * inv;
        const float4 sv = *reinterpret_cast<const float4*>(stamp + h * 128 + w0);
        const float svj[4] = {sv.x, sv.y, sv.z, sv.w};
#pragma unroll
        for (int j = 0; j < 4; ++j) {
            const int w = w0 + j;
            const int t = w - 17;
            const int bar = t / 3;
            const bool valid = (t >= 0) && (t <= 93) && (t - bar * 3 == 0);
            const int bhv = __shfl(bt, valid ? bar : 0);
            const float barv = (valid && h < bhv) ? 1.0f : 0.0f;
            vals[5 * j + 0] = svj[j];
            vals[5 * j + 1] = 0.0f;          // ch1 added by atomics later
            vals[5 * j + 2] = rowv;
            vals[5 * j + 3] = ndv;
            vals[5 * j + 4] = barv;
        }
    };
    auto stage = [&](int c, const float* vals) {
        float4* lw = reinterpret_cast<float4*>(&buf[c][tid * 20]);  // 80B, 16-aligned
        const float4* src = reinterpret_cast<const float4*>(vals);
#pragma unroll
        for (int k = 0; k < 5; ++k) lw[k] = src[k];
    };
    auto flush = [&](int c) {
        // stride-1 float4 per lane: each wave store = contiguous 1024B full lines
        float4* dst = reinterpret_cast<float4*>(out) +
                      (size_t)b * 20480 + (size_t)part * 2560 + (size_t)c * 1280;
        const float4* lr = reinterpret_cast<const float4*>(buf[c]);
#pragma unroll
        for (int it = 0; it < 5; ++it) {
            const int f = it * 256 + tid;
            dst[f] = lr[f];
        }
    };

    alignas(16) float valsA[20], valsB[20];
    compute(0, valsA);
    stage(0, valsA);
    __syncthreads();
    compute(1, valsB);      // independent of buf0 reads -> compiler interleaves
    stage(1, valsB);        // buf1 writes need only the barrier BELOW before reads
    flush(0);               // stores of chunk 0 overlap compute/stage of chunk 1
    __syncthreads();
    flush(1);

    // ---- fused scatter: order ch1=0 stores before atomics ----
    __syncthreads();        // implies vmcnt drain: block's plain stores complete
    if (tid < 32) {
        const int r = coords[2 * tid], c = coords[2 * tid + 1];
        if ((r >> 4) == part)   // block owns rows [part*16, part*16+16)
            atomicAdd(out + ((size_t)b * 16384 + (size_t)(r * 128 + c)) * 5 + 1,
                      __shfl(v, tid));   // = x[b][tid]; duplicates sum via atomic
    }
}

extern "C" void kernel_launch(void* const* d_in, const int* in_sizes, int n_in,
                              void* d_out, int out_size, void* d_ws, size_t ws_size,
                              hipStream_t stream) {
    const float* inputs = (const float*)d_in[0];   // [512,32]
    const float* stamp  = (const float*)d_in[1];   // [128,128,1]
    const int*   coords = (const int*)d_in[2];     // [32,2]
    float* out = (float*)d_out;                    // [512,128,128,5]

    di_main<<<4096, 256, 0, stream>>>(inputs, stamp, coords, out);
}